// Round 14
// baseline (139.535 us; speedup 1.0000x reference)
//
#include <hip/hip_runtime.h>
#include <hip/hip_bf16.h>

#define B_ 4
#define L_ 8192
#define D_ 256
#define J_ 13

typedef __attribute__((ext_vector_type(4))) float f32x4;
typedef __attribute__((ext_vector_type(2))) float v2f;
typedef __attribute__((ext_vector_type(8))) short bf16x8;
typedef __attribute__((ext_vector_type(8))) unsigned short u16x8;

__device__ __forceinline__ void async_copy16(const void* g, void* l) {
    __builtin_amdgcn_global_load_lds(
        (const __attribute__((address_space(1))) void*)g,
        (__attribute__((address_space(3))) void*)l, 16, 0, 0);
}

// hardware packed f32->bf16x2 convert (RNE); no builtin on gfx950 -> inline asm
__device__ __forceinline__ unsigned int cvtpk(float lo, float hi) {
    unsigned int r;
    asm("v_cvt_pk_bf16_f32 %0, %1, %2" : "=v"(r) : "v"(lo), "v"(hi));
    return r;
}
__device__ __forceinline__ unsigned short packbf1(float a) {
    return (unsigned short)((__float_as_uint(a) + 0x8000u) >> 16);
}
__device__ __forceinline__ float bflo(unsigned int u) { return __uint_as_float(u << 16); }
__device__ __forceinline__ float bfhi(unsigned int u) { return __uint_as_float(u & 0xFFFF0000u); }

// ---------------- K1: fused wt-transpose (blocks 0..31) + RMSNorm/transpose ------
__global__ void rms_wt_kernel(const float* __restrict__ x, const float* __restrict__ scale,
                              ushort* __restrict__ xtb,
                              const float* __restrict__ W, ushort* __restrict__ Wt) {
    __shared__ __align__(16) float sm[32 * 260 + 32];
    int blk = blockIdx.x;
    int tid = threadIdx.x;
    if (blk < 32) {
        float (*tile)[65] = (float(*)[65])sm;
        int dt = blk >> 3, et = blk & 7;
        int d0 = dt * 64, e0 = et * 64;
#pragma unroll
        for (int k = 0; k < 16; ++k) {
            int i = tid + k * 256;
            int r = i >> 6, c = i & 63;
            tile[r][c] = W[(d0 + r) * 512 + e0 + c];
        }
        __syncthreads();
#pragma unroll
        for (int k = 0; k < 16; ++k) {
            int i = tid + k * 256;
            int r = i >> 6, c = i & 63;
            Wt[(e0 + r) * 256 + d0 + c] = packbf1(tile[c][r]);
        }
        return;
    }
    blk -= 32;                        // b*256 + ltile
    float (*tile)[260] = (float(*)[260])sm;
    float* invl = sm + 32 * 260;
    int b  = blk >> 8;
    int l0 = (blk & 255) << 5;
    const float* src = x + ((size_t)(b * L_ + l0)) * D_;
#pragma unroll
    for (int k = 0; k < 8; ++k) {
        int i = tid + k * 256;         // 2048 float4 slots
        int r = i >> 6, c4 = i & 63;
        *(float4*)&tile[r][c4 * 4] = *(const float4*)(src + r * D_ + c4 * 4);
    }
    __syncthreads();
    int wave = tid >> 6, lane = tid & 63;
#pragma unroll
    for (int rr = 0; rr < 8; ++rr) {
        int r = wave * 8 + rr;
        float s = 0.f;
#pragma unroll
        for (int q = 0; q < 4; ++q) { float v = tile[r][lane + 64 * q]; s += v * v; }
#pragma unroll
        for (int off = 32; off; off >>= 1) s += __shfl_xor(s, off);
        if (lane == 0) invl[r] = rsqrtf(s * (1.0f / 256.0f) + 1e-6f);
    }
    __syncthreads();
    uint* dst32 = (uint*)xtb;
#pragma unroll
    for (int k = 0; k < 8; ++k) {
        int i = tid + k * 256;         // 2048 (d, l-quad) slots
        int d = i >> 3, lp2 = (i & 7) * 4;
        float s = scale[d];
        uint u0 = cvtpk(tile[lp2][d]     * invl[lp2]     * s,
                        tile[lp2 + 1][d] * invl[lp2 + 1] * s);
        uint u1 = cvtpk(tile[lp2 + 2][d] * invl[lp2 + 2] * s,
                        tile[lp2 + 3][d] * invl[lp2 + 3] * s);
        uint2 uv; uv.x = u0; uv.y = u1;
        *(uint2*)(dst32 + ((((size_t)(b * D_ + d)) * L_ + l0 + lp2) >> 1)) = uv;
    }
}

// ---------------- K2: 13-level dilated depthwise cascade + gelu ------------------
// Proven R5 structure (R6/R7 restructures spilled; strided-tail re-derived:
// transpose barriers eat the savings). 1ch/block, 256 thr, 40KB LDS.
#define LEVEL_SMALL(d, jj, buf)                                                  \
    do {                                                                         \
        uint4 pk;                                                                \
        pk.x = cvtpk(cc[8][0],  cc[8][1]);  pk.y = cvtpk(cc[9][0],  cc[9][1]);   \
        pk.z = cvtpk(cc[10][0], cc[10][1]); pk.w = cvtpk(cc[11][0], cc[11][1]);  \
        *(uint4*)((buf) + slot + 16) = pk;                                       \
        pk.x = cvtpk(cc[12][0], cc[12][1]); pk.y = cvtpk(cc[13][0], cc[13][1]);  \
        pk.z = cvtpk(cc[14][0], cc[14][1]); pk.w = cvtpk(cc[15][0], cc[15][1]);  \
        *(uint4*)((buf) + slot + 24) = pk;                                       \
        __syncthreads();                                                         \
        v2f pt2[8];                                                              \
        if (ct > 0) {                                                            \
            uint4 a  = *(const uint4*)((buf) + slot - 40 + 16);                  \
            uint4 bq = *(const uint4*)((buf) + slot - 40 + 24);                  \
            uint uu[8] = {a.x, a.y, a.z, a.w, bq.x, bq.y, bq.z, bq.w};           \
            _Pragma("unroll") for (int q = 0; q < 8; ++q) {                      \
                pt2[q][0] = bflo(uu[q]); pt2[q][1] = bfhi(uu[q]); }              \
        } else { _Pragma("unroll") for (int q = 0; q < 8; ++q) pt2[q] = (v2f)0.f; } \
        float wjs = w[((jj) + 1) * D_ + c];                                      \
        v2f wh10 = (v2f)(wjs * h10), wh11 = (v2f)(wjs * h11);                    \
        v2f h00v = (v2f)h00, h01v = (v2f)h01;                                    \
        _Pragma("unroll")                                                        \
        for (int p = 15; p >= 0; --p) {                                          \
            v2f pv;                                                              \
            if ((d) == 1) {                                                      \
                pv[0] = (p == 0) ? pt2[7][1] : cc[p - 1][1];                     \
                pv[1] = cc[p][0];                                                \
            } else {                                                             \
                const int hd = (d) >> 1;                                         \
                pv = (p >= hd) ? cc[p - hd] : pt2[8 + p - hd];                   \
            }                                                                    \
            v2f nv = h00v * pv + h01v * cc[p];                                   \
            y[p] += wh10 * pv;                                                   \
            y[p] += wh11 * cc[p];                                                \
            cc[p] = nv;                                                          \
        }                                                                        \
    } while (0)

__global__ void __launch_bounds__(256) cascade_kernel(
    const ushort* __restrict__ xt, const float* __restrict__ h0,
    const float* __restrict__ h1, const float* __restrict__ w,
    ushort* __restrict__ ygt) {
    __shared__ __align__(16) ushort ex[2 * 256 * 40];   // 40 KB double-buffered
    ushort* bufA = ex;
    ushort* bufB = ex + 256 * 40;
    int blk = blockIdx.x;                  // b*256 + c
    int b = blk >> 8;
    int c = blk & 255;
    int ct = threadIdx.x;                  // 0..255 = l-chunk
    int slot = ct * 40;                    // ushort offset, 80B stride
    float h00 = h0[2*c], h01 = h0[2*c+1];
    float h10 = h1[2*c], h11 = h1[2*c+1];
    float w0 = w[c], wlast = w[14 * D_ + c];

    const ushort* src = xt + ((size_t)(b * D_ + c)) * L_ + ct * 32;
    v2f cc[16], y[16];
#pragma unroll
    for (int m = 0; m < 4; ++m) {
        u16x8 v = *(const u16x8*)(src + m * 8);
#pragma unroll
        for (int p = 0; p < 4; ++p) {
            cc[m*4+p][0] = __uint_as_float(((uint)v[2*p])     << 16);
            cc[m*4+p][1] = __uint_as_float(((uint)v[2*p + 1]) << 16);
        }
    }
    {
        v2f w0v = (v2f)w0;
#pragma unroll
        for (int p = 0; p < 16; ++p) y[p] = w0v * cc[p];
    }

    LEVEL_SMALL(1, 0, bufA);
    LEVEL_SMALL(2, 1, bufB);
    LEVEL_SMALL(4, 2, bufA);
    LEVEL_SMALL(8, 3, bufB);
    LEVEL_SMALL(16, 4, bufA);

#pragma unroll 1
    for (int j = 5; j < J_; ++j) {
        int dT = 1 << (j - 5);
        float wjs = w[(j + 1) * D_ + c];
        v2f wh10 = (v2f)(wjs * h10), wh11 = (v2f)(wjs * h11);
        v2f h00v = (v2f)h00, h01v = (v2f)h01;
        ushort* buf = (j & 1) ? bufB : bufA;
#pragma unroll
        for (int m = 0; m < 4; ++m) {
            uint4 pk;
            pk.x = cvtpk(cc[4*m][0],   cc[4*m][1]);
            pk.y = cvtpk(cc[4*m+1][0], cc[4*m+1][1]);
            pk.z = cvtpk(cc[4*m+2][0], cc[4*m+2][1]);
            pk.w = cvtpk(cc[4*m+3][0], cc[4*m+3][1]);
            *(uint4*)(buf + slot + 8 * m) = pk;
        }
        __syncthreads();
        bool has = (ct >= dT);
        int pbase = slot - dT * 40;
        v2f pv2[16];
        if (has) {
#pragma unroll
            for (int m = 0; m < 4; ++m) {
                uint4 a = *(const uint4*)(buf + pbase + 8 * m);
                uint uu[4] = {a.x, a.y, a.z, a.w};
#pragma unroll
                for (int q = 0; q < 4; ++q) {
                    pv2[4*m+q][0] = bflo(uu[q]);
                    pv2[4*m+q][1] = bfhi(uu[q]);
                }
            }
        } else {
#pragma unroll
            for (int q = 0; q < 16; ++q) pv2[q] = (v2f)0.f;
        }
#pragma unroll
        for (int p = 0; p < 16; ++p) {
            v2f nv = h00v * pv2[p] + h01v * cc[p];
            y[p] += wh10 * pv2[p];
            y[p] += wh11 * cc[p];
            cc[p] = nv;
        }
    }
    // ---- epilogue: + wlast*a, gelu = v*sigmoid(2u); exp2 with folded log2e ----
    ushort* dst = ygt + ((size_t)(b * D_ + c)) * L_ + ct * 32;
    v2f wl2 = (v2f)wlast;
    v2f c1v = (v2f)0.044715f, onev = (v2f)1.f;
    v2f k2v = (v2f)-2.3022083f;   // -1.5957691216 * log2(e)
#pragma unroll
    for (int m = 0; m < 4; ++m) {
        uint pk4[4];
#pragma unroll
        for (int q = 0; q < 4; ++q) {
            int p = 4*m + q;
            v2f v  = y[p] + wl2 * cc[p];
            v2f vv = v * v;
            v2f tt = c1v * vv + onev;
            v2f q2 = k2v * (v * tt);
            float g0 = v[0] * __builtin_amdgcn_rcpf(1.f + exp2f(q2[0]));
            float g1 = v[1] * __builtin_amdgcn_rcpf(1.f + exp2f(q2[1]));
            pk4[q] = cvtpk(g0, g1);
        }
        uint4 pk; pk.x = pk4[0]; pk.y = pk4[1]; pk.z = pk4[2]; pk.w = pk4[3];
        *(uint4*)(dst + 8 * m) = pk;
    }
}

// ---------------- K3: bf16 MFMA GEMM + bias + GLU + residual ---------------------
// R14: BK 64 -> 128. Halves the kc loop: 10 barriers/block -> 6 (latency-bound
// kernel; barrier drains dominate). LDS 48KB -> 3 blocks/CU (vs 4): trades 25%
// occupancy for 40% fewer barriers. Registers: ar[2][4]=32 VGPR + acc 32 AGPR
// + ~40 working ~= 105 combined < (256,3) cap ~170 -- no spill (frontier mapped
// R3/R7/R10/R12). Granule space 0..15; XOR swizzle low-3 bits (bit3 = dd/kk-half
// preserved write+read). B-staging LDS dest stays base+lane*16 (m104 rule).
// vmcnt(8): drains 4 B-copies, keeps 8 A-prefetch in flight across the barrier.
__global__ void __launch_bounds__(256, 3) gemm_kernel(
    const ushort* __restrict__ ygt, const ushort* __restrict__ Wt,
    const float* __restrict__ cb, const float* __restrict__ x,
    float* __restrict__ out) {
    __shared__ __align__(16) char smem[49152];
    ushort* As = (ushort*)smem;            // [128 l][128 d] swz  32 KB
    ushort* Bs = As + 128 * 128;           // [64 e-rows][128 d] swz  16 KB
    int hw = blockIdx.x;                   // 2048 blocks; XCD = hw & 7
    int blk = (hw & 7) * 256 + (hw >> 3);  // bijective: siblings -> same XCD
    int b = blk >> 9;
    int rem = blk & 511;
    int ltile = rem >> 3, et = rem & 7;
    int l0 = ltile * 128, e0 = et * 32;
    int tid = threadIdx.x;
    int wave = tid >> 6, lane = tid & 63;
    int wm = wave >> 1, wn = wave & 1;
    int m0 = wm * 64;

    // B staging: 4 copies/thread; dest granule bg=lane&15 at row r -> linear lane*16
    int brow_in = lane >> 4;               // 0..3
    int bg = lane & 15;

    // A staging: thread owns 4(d) x 8(l); dd in {0,1} extends to d+64
    int lb = tid & 15, db = tid >> 4;      // lb: l-octet, db: d-quad
    const ushort* aPtr = ygt + ((size_t)(b * D_ + db * 4)) * L_ + l0 + lb * 8;

    f32x4 acc[4][2];
#pragma unroll
    for (int i = 0; i < 4; ++i)
#pragma unroll
        for (int j = 0; j < 2; ++j) acc[i][j] = (f32x4)0.f;

    uint4 ar[2][4];
#pragma unroll
    for (int dd = 0; dd < 2; ++dd)
#pragma unroll
        for (int rr = 0; rr < 4; ++rr)
            ar[dd][rr] = *(const uint4*)(aPtr + (size_t)(dd * 64 + rr) * L_);

#pragma unroll
    for (int kc = 0; kc < 2; ++kc) {
        __syncthreads();
        // --- B tile: async global->LDS (4 x 16B per thread), oldest vmem ops ---
#pragma unroll
        for (int v = 0; v < 4; ++v) {
            int r = wave * 16 + v * 4 + brow_in;        // 0..63
            int e = (r < 32) ? (e0 + r) : (256 + e0 + (r - 32));
            int gs = bg ^ (r & 7);                       // pre-swizzled source
            async_copy16(Wt + e * 256 + kc * 128 + gs * 8,
                         Bs + r * 128 + bg * 8);         // linear dest
        }
        __builtin_amdgcn_sched_barrier(0);   // pin async copies before younger loads
        // --- A tile: transpose-pack ar (2 x 4d x 8l) -> 16 x ds_write_b64 ---
#pragma unroll
        for (int dd = 0; dd < 2; ++dd) {
#pragma unroll
            for (int j = 0; j < 8; ++j) {
                int q = j >> 1;
                uint sel = (j & 1) ? 0x07060302u : 0x05040100u;
                uint w0 = __builtin_amdgcn_perm(((const uint*)&ar[dd][1])[q],
                                                ((const uint*)&ar[dd][0])[q], sel);
                uint w1 = __builtin_amdgcn_perm(((const uint*)&ar[dd][3])[q],
                                                ((const uint*)&ar[dd][2])[q], sel);
                uint2 wv; wv.x = w0; wv.y = w1;
                int r = lb * 8 + j;
                int g = (db >> 1) + dd * 8;              // granule 0..15
                int gp = g ^ j ^ (lb & 7);               // low-3 XOR, bit3 kept
                *(uint2*)(As + r * 128 + gp * 8 + (db & 1) * 4) = wv;
            }
        }
        // --- prefetch next-kc A slab (8 younger vmem ops, survive the barrier) ---
        if (kc < 1) {
#pragma unroll
            for (int dd = 0; dd < 2; ++dd)
#pragma unroll
                for (int rr = 0; rr < 4; ++rr)
                    ar[dd][rr] = *(const uint4*)(aPtr + (size_t)(128 + dd * 64 + rr) * L_);
            __builtin_amdgcn_sched_barrier(0);
            asm volatile("s_waitcnt vmcnt(8) lgkmcnt(0)" ::: "memory");
        } else {
            __builtin_amdgcn_sched_barrier(0);
            asm volatile("s_waitcnt vmcnt(0) lgkmcnt(0)" ::: "memory");
        }
        __builtin_amdgcn_s_barrier();
        __builtin_amdgcn_sched_barrier(0);
        // --- compute: bfr preloaded, af streamed ---
#pragma unroll
        for (int kk = 0; kk < 4; ++kk) {
            bf16x8 bfr[2];
            int g = kk * 4 + (lane >> 4);                // granule 0..15
            int gp = (g ^ (lane & 7)) * 8;
#pragma unroll
            for (int nt = 0; nt < 2; ++nt) {
                int n = nt * 32 + wn * 16 + (lane & 15);   // n&7 == lane&7
                bfr[nt] = *(const bf16x8*)(Bs + n * 128 + gp);
            }
#pragma unroll
            for (int mt = 0; mt < 4; ++mt) {
                int rowA = m0 + mt * 16 + (lane & 15);
                int gpA = (g ^ (rowA & 7) ^ ((rowA >> 3) & 7)) * 8;
                bf16x8 af = *(const bf16x8*)(As + rowA * 128 + gpA);
#pragma unroll
                for (int nt = 0; nt < 2; ++nt)
                    acc[mt][nt] = __builtin_amdgcn_mfma_f32_16x16x32_bf16(
                        af, bfr[nt], acc[mt][nt], 0, 0, 0);
            }
        }
    }
    // --- prefetch residual x BEFORE the epilogue barriers ---
    float4 xf[4];
#pragma unroll
    for (int k = 0; k < 4; ++k) {
        int i = tid + k * 256;             // 0..1023
        int ll = i >> 3, e4 = i & 7;
        xf[k] = *(const float4*)(x + ((size_t)(b * L_ + l0 + ll)) * D_ + e0 + e4 * 4);
    }
    __syncthreads();
    float* epi = (float*)smem;             // [128 l][32 e] = 16 KB
    int row_in = (lane >> 4) * 4;
    int col = lane & 15;
#pragma unroll
    for (int mt = 0; mt < 4; ++mt) {
        f32x4 uacc = acc[mt][0];
        f32x4 vacc = acc[mt][1];
        int ee = wn * 16 + col;
        float bu = cb[e0 + ee], bv = cb[256 + e0 + ee];
#pragma unroll
        for (int r = 0; r < 4; ++r) {
            int ll = m0 + mt * 16 + row_in + r;
            float u = uacc[r] + bu;
            float v = vacc[r] + bv;
            float g = u * __builtin_amdgcn_rcpf(1.f + __expf(-v));
            epi[ll * 32 + (ee ^ ((ll & 4) ? 16 : 0))] = g;
        }
    }
    __syncthreads();
#pragma unroll
    for (int k = 0; k < 4; ++k) {
        int i = tid + k * 256;             // 0..1023
        int ll = i >> 3, e4 = i & 7;
        int exo = (e4 * 4) ^ ((ll & 4) ? 16 : 0);
        float4 gv = *(const float4*)(epi + ll * 32 + exo);
        size_t gidx = ((size_t)(b * L_ + l0 + ll)) * D_ + e0 + e4 * 4;
        float4 ov;
        ov.x = gv.x + xf[k].x; ov.y = gv.y + xf[k].y;
        ov.z = gv.z + xf[k].z; ov.w = gv.w + xf[k].w;
        *(float4*)(out + gidx) = ov;
    }
}

extern "C" void kernel_launch(void* const* d_in, const int* in_sizes, int n_in,
                              void* d_out, int out_size, void* d_ws, size_t ws_size,
                              hipStream_t stream) {
    const float* x  = (const float*)d_in[0];
    const float* rs = (const float*)d_in[1];
    const float* h0 = (const float*)d_in[2];
    const float* h1 = (const float*)d_in[3];
    const float* w  = (const float*)d_in[4];
    const float* cw = (const float*)d_in[5];
    const float* cb = (const float*)d_in[6];
    float* out = (float*)d_out;
    char* ws = (char*)d_ws;

    ushort* xtb = (ushort*)ws;                       // 16,777,216 B (bf16)
    ushort* ygt = (ushort*)(ws + 16777216);          // 16,777,216 B (bf16)
    ushort* Wt  = (ushort*)(ws + 33554432);          //    262,144 B (bf16)

    rms_wt_kernel<<<1056, 256, 0, stream>>>(x, rs, xtb, cw, Wt);
    cascade_kernel<<<1024, 256, 0, stream>>>(xtb, h0, h1, w, ygt);
    gemm_kernel<<<2048, 256, 0, stream>>>(ygt, Wt, cb, x, out);
}

// Round 15
// 137.340 us; speedup vs baseline: 1.0160x; 1.0160x over previous
//
#include <hip/hip_runtime.h>
#include <hip/hip_bf16.h>

#define B_ 4
#define L_ 8192
#define D_ 256
#define J_ 13

typedef __attribute__((ext_vector_type(4))) float f32x4;
typedef __attribute__((ext_vector_type(2))) float v2f;
typedef __attribute__((ext_vector_type(8))) short bf16x8;
typedef __attribute__((ext_vector_type(8))) unsigned short u16x8;

__device__ __forceinline__ void async_copy16(const void* g, void* l) {
    __builtin_amdgcn_global_load_lds(
        (const __attribute__((address_space(1))) void*)g,
        (__attribute__((address_space(3))) void*)l, 16, 0, 0);
}

// hardware packed f32->bf16x2 convert (RNE); no builtin on gfx950 -> inline asm
__device__ __forceinline__ unsigned int cvtpk(float lo, float hi) {
    unsigned int r;
    asm("v_cvt_pk_bf16_f32 %0, %1, %2" : "=v"(r) : "v"(lo), "v"(hi));
    return r;
}
__device__ __forceinline__ unsigned short packbf1(float a) {
    return (unsigned short)((__float_as_uint(a) + 0x8000u) >> 16);
}
__device__ __forceinline__ float bflo(unsigned int u) { return __uint_as_float(u << 16); }
__device__ __forceinline__ float bfhi(unsigned int u) { return __uint_as_float(u & 0xFFFF0000u); }

// ---------------- K1: fused wt-transpose (blocks 0..31) + RMSNorm/transpose ------
__global__ void rms_wt_kernel(const float* __restrict__ x, const float* __restrict__ scale,
                              ushort* __restrict__ xtb,
                              const float* __restrict__ W, ushort* __restrict__ Wt) {
    __shared__ __align__(16) float sm[32 * 260 + 32];
    int blk = blockIdx.x;
    int tid = threadIdx.x;
    if (blk < 32) {
        float (*tile)[65] = (float(*)[65])sm;
        int dt = blk >> 3, et = blk & 7;
        int d0 = dt * 64, e0 = et * 64;
#pragma unroll
        for (int k = 0; k < 16; ++k) {
            int i = tid + k * 256;
            int r = i >> 6, c = i & 63;
            tile[r][c] = W[(d0 + r) * 512 + e0 + c];
        }
        __syncthreads();
#pragma unroll
        for (int k = 0; k < 16; ++k) {
            int i = tid + k * 256;
            int r = i >> 6, c = i & 63;
            Wt[(e0 + r) * 256 + d0 + c] = packbf1(tile[c][r]);
        }
        return;
    }
    blk -= 32;                        // b*256 + ltile
    float (*tile)[260] = (float(*)[260])sm;
    float* invl = sm + 32 * 260;
    int b  = blk >> 8;
    int l0 = (blk & 255) << 5;
    const float* src = x + ((size_t)(b * L_ + l0)) * D_;
#pragma unroll
    for (int k = 0; k < 8; ++k) {
        int i = tid + k * 256;         // 2048 float4 slots
        int r = i >> 6, c4 = i & 63;
        *(float4*)&tile[r][c4 * 4] = *(const float4*)(src + r * D_ + c4 * 4);
    }
    __syncthreads();
    int wave = tid >> 6, lane = tid & 63;
#pragma unroll
    for (int rr = 0; rr < 8; ++rr) {
        int r = wave * 8 + rr;
        float s = 0.f;
#pragma unroll
        for (int q = 0; q < 4; ++q) { float v = tile[r][lane + 64 * q]; s += v * v; }
#pragma unroll
        for (int off = 32; off; off >>= 1) s += __shfl_xor(s, off);
        if (lane == 0) invl[r] = rsqrtf(s * (1.0f / 256.0f) + 1e-6f);
    }
    __syncthreads();
    uint* dst32 = (uint*)xtb;
#pragma unroll
    for (int k = 0; k < 8; ++k) {
        int i = tid + k * 256;         // 2048 (d, l-quad) slots
        int d = i >> 3, lp2 = (i & 7) * 4;
        float s = scale[d];
        uint u0 = cvtpk(tile[lp2][d]     * invl[lp2]     * s,
                        tile[lp2 + 1][d] * invl[lp2 + 1] * s);
        uint u1 = cvtpk(tile[lp2 + 2][d] * invl[lp2 + 2] * s,
                        tile[lp2 + 3][d] * invl[lp2 + 3] * s);
        uint2 uv; uv.x = u0; uv.y = u1;
        *(uint2*)(dst32 + ((((size_t)(b * D_ + d)) * L_ + l0 + lp2) >> 1)) = uv;
    }
}

// ---------------- K2: 13-level dilated depthwise cascade + gelu ------------------
// Proven R5 structure (R6/R7 restructures spilled; strided-tail re-derived:
// transpose barriers eat the savings). 1ch/block, 256 thr, 40KB LDS.
#define LEVEL_SMALL(d, jj, buf)                                                  \
    do {                                                                         \
        uint4 pk;                                                                \
        pk.x = cvtpk(cc[8][0],  cc[8][1]);  pk.y = cvtpk(cc[9][0],  cc[9][1]);   \
        pk.z = cvtpk(cc[10][0], cc[10][1]); pk.w = cvtpk(cc[11][0], cc[11][1]);  \
        *(uint4*)((buf) + slot + 16) = pk;                                       \
        pk.x = cvtpk(cc[12][0], cc[12][1]); pk.y = cvtpk(cc[13][0], cc[13][1]);  \
        pk.z = cvtpk(cc[14][0], cc[14][1]); pk.w = cvtpk(cc[15][0], cc[15][1]);  \
        *(uint4*)((buf) + slot + 24) = pk;                                       \
        __syncthreads();                                                         \
        v2f pt2[8];                                                              \
        if (ct > 0) {                                                            \
            uint4 a  = *(const uint4*)((buf) + slot - 40 + 16);                  \
            uint4 bq = *(const uint4*)((buf) + slot - 40 + 24);                  \
            uint uu[8] = {a.x, a.y, a.z, a.w, bq.x, bq.y, bq.z, bq.w};           \
            _Pragma("unroll") for (int q = 0; q < 8; ++q) {                      \
                pt2[q][0] = bflo(uu[q]); pt2[q][1] = bfhi(uu[q]); }              \
        } else { _Pragma("unroll") for (int q = 0; q < 8; ++q) pt2[q] = (v2f)0.f; } \
        float wjs = w[((jj) + 1) * D_ + c];                                      \
        v2f wh10 = (v2f)(wjs * h10), wh11 = (v2f)(wjs * h11);                    \
        v2f h00v = (v2f)h00, h01v = (v2f)h01;                                    \
        _Pragma("unroll")                                                        \
        for (int p = 15; p >= 0; --p) {                                          \
            v2f pv;                                                              \
            if ((d) == 1) {                                                      \
                pv[0] = (p == 0) ? pt2[7][1] : cc[p - 1][1];                     \
                pv[1] = cc[p][0];                                                \
            } else {                                                             \
                const int hd = (d) >> 1;                                         \
                pv = (p >= hd) ? cc[p - hd] : pt2[8 + p - hd];                   \
            }                                                                    \
            v2f nv = h00v * pv + h01v * cc[p];                                   \
            y[p] += wh10 * pv;                                                   \
            y[p] += wh11 * cc[p];                                                \
            cc[p] = nv;                                                          \
        }                                                                        \
    } while (0)

__global__ void __launch_bounds__(256) cascade_kernel(
    const ushort* __restrict__ xt, const float* __restrict__ h0,
    const float* __restrict__ h1, const float* __restrict__ w,
    ushort* __restrict__ ygt) {
    __shared__ __align__(16) ushort ex[2 * 256 * 40];   // 40 KB double-buffered
    ushort* bufA = ex;
    ushort* bufB = ex + 256 * 40;
    int blk = blockIdx.x;                  // b*256 + c
    int b = blk >> 8;
    int c = blk & 255;
    int ct = threadIdx.x;                  // 0..255 = l-chunk
    int slot = ct * 40;                    // ushort offset, 80B stride
    float h00 = h0[2*c], h01 = h0[2*c+1];
    float h10 = h1[2*c], h11 = h1[2*c+1];
    float w0 = w[c], wlast = w[14 * D_ + c];

    const ushort* src = xt + ((size_t)(b * D_ + c)) * L_ + ct * 32;
    v2f cc[16], y[16];
#pragma unroll
    for (int m = 0; m < 4; ++m) {
        u16x8 v = *(const u16x8*)(src + m * 8);
#pragma unroll
        for (int p = 0; p < 4; ++p) {
            cc[m*4+p][0] = __uint_as_float(((uint)v[2*p])     << 16);
            cc[m*4+p][1] = __uint_as_float(((uint)v[2*p + 1]) << 16);
        }
    }
    {
        v2f w0v = (v2f)w0;
#pragma unroll
        for (int p = 0; p < 16; ++p) y[p] = w0v * cc[p];
    }

    LEVEL_SMALL(1, 0, bufA);
    LEVEL_SMALL(2, 1, bufB);
    LEVEL_SMALL(4, 2, bufA);
    LEVEL_SMALL(8, 3, bufB);
    LEVEL_SMALL(16, 4, bufA);

#pragma unroll 1
    for (int j = 5; j < J_; ++j) {
        int dT = 1 << (j - 5);
        float wjs = w[(j + 1) * D_ + c];
        v2f wh10 = (v2f)(wjs * h10), wh11 = (v2f)(wjs * h11);
        v2f h00v = (v2f)h00, h01v = (v2f)h01;
        ushort* buf = (j & 1) ? bufB : bufA;
#pragma unroll
        for (int m = 0; m < 4; ++m) {
            uint4 pk;
            pk.x = cvtpk(cc[4*m][0],   cc[4*m][1]);
            pk.y = cvtpk(cc[4*m+1][0], cc[4*m+1][1]);
            pk.z = cvtpk(cc[4*m+2][0], cc[4*m+2][1]);
            pk.w = cvtpk(cc[4*m+3][0], cc[4*m+3][1]);
            *(uint4*)(buf + slot + 8 * m) = pk;
        }
        __syncthreads();
        bool has = (ct >= dT);
        int pbase = slot - dT * 40;
        v2f pv2[16];
        if (has) {
#pragma unroll
            for (int m = 0; m < 4; ++m) {
                uint4 a = *(const uint4*)(buf + pbase + 8 * m);
                uint uu[4] = {a.x, a.y, a.z, a.w};
#pragma unroll
                for (int q = 0; q < 4; ++q) {
                    pv2[4*m+q][0] = bflo(uu[q]);
                    pv2[4*m+q][1] = bfhi(uu[q]);
                }
            }
        } else {
#pragma unroll
            for (int q = 0; q < 16; ++q) pv2[q] = (v2f)0.f;
        }
#pragma unroll
        for (int p = 0; p < 16; ++p) {
            v2f nv = h00v * pv2[p] + h01v * cc[p];
            y[p] += wh10 * pv2[p];
            y[p] += wh11 * cc[p];
            cc[p] = nv;
        }
    }
    // ---- epilogue: + wlast*a, gelu = v*sigmoid(2u); exp2 with folded log2e ----
    ushort* dst = ygt + ((size_t)(b * D_ + c)) * L_ + ct * 32;
    v2f wl2 = (v2f)wlast;
    v2f c1v = (v2f)0.044715f, onev = (v2f)1.f;
    v2f k2v = (v2f)-2.3022083f;   // -1.5957691216 * log2(e)
#pragma unroll
    for (int m = 0; m < 4; ++m) {
        uint pk4[4];
#pragma unroll
        for (int q = 0; q < 4; ++q) {
            int p = 4*m + q;
            v2f v  = y[p] + wl2 * cc[p];
            v2f vv = v * v;
            v2f tt = c1v * vv + onev;
            v2f q2 = k2v * (v * tt);
            float g0 = v[0] * __builtin_amdgcn_rcpf(1.f + exp2f(q2[0]));
            float g1 = v[1] * __builtin_amdgcn_rcpf(1.f + exp2f(q2[1]));
            pk4[q] = cvtpk(g0, g1);
        }
        uint4 pk; pk.x = pk4[0]; pk.y = pk4[1]; pk.z = pk4[2]; pk.w = pk4[3];
        *(uint4*)(dst + 8 * m) = pk;
    }
}

// ---------------- K3: bf16 MFMA GEMM + bias + GLU + residual ---------------------
// R14 POST-MORTEM: BK=128 regressed (139.5; barrier cut lost to occupancy 4->3).
// Reverted to the R12/R13 session-best config: narrow tile 128l x 32e,
// acc[4][2]=32 AGPR at the (256,4) 4-block/CU tier, BK=64, af-streamed compute,
// residual-x prefetched above the epilogue barriers. 137.9-138.1us.
__global__ void __launch_bounds__(256, 4) gemm_kernel(
    const ushort* __restrict__ ygt, const ushort* __restrict__ Wt,
    const float* __restrict__ cb, const float* __restrict__ x,
    float* __restrict__ out) {
    __shared__ __align__(16) char smem[24576];
    ushort* As = (ushort*)smem;            // [128 l][8 granules, swz2]  16 KB
    ushort* Bs = As + 128 * 64;            // [64 e-rows][8 granules, swz1] 8 KB
    int hw = blockIdx.x;                   // 2048 blocks; XCD = hw & 7
    int blk = (hw & 7) * 256 + (hw >> 3);  // bijective: siblings -> same XCD
    int b = blk >> 9;
    int rem = blk & 511;
    int ltile = rem >> 3, et = rem & 7;
    int l0 = ltile * 128, e0 = et * 32;
    int tid = threadIdx.x;
    int wave = tid >> 6, lane = tid & 63;
    int wm = wave >> 1, wn = wave & 1;
    int m0 = wm * 64;

    int srow_in = (lane >> 3);             // B staging: 0..7 within volley
    int sg = lane & 7;                     // swizzled granule g'
    int sgg = sg ^ srow_in;                // unswizzled granule g

    // A staging: thread owns a 4(d) x 8(l) sub-block of the 64x128 ygt slab
    int lb = tid & 15, db = tid >> 4;      // lb: l-octet, db: d-quad
    const ushort* aPtr = ygt + ((size_t)(b * D_ + db * 4)) * L_ + l0 + lb * 8;

    f32x4 acc[4][2];
#pragma unroll
    for (int i = 0; i < 4; ++i)
#pragma unroll
        for (int j = 0; j < 2; ++j) acc[i][j] = (f32x4)0.f;

    uint4 ar[4];
#pragma unroll
    for (int rr = 0; rr < 4; ++rr) ar[rr] = *(const uint4*)(aPtr + rr * L_);

#pragma unroll
    for (int kc = 0; kc < 4; ++kc) {
        __syncthreads();
        // --- B tile: async global->LDS (2 x 16B per thread), oldest vmem ops ---
#pragma unroll
        for (int v = 0; v < 2; ++v) {
            int r = wave * 16 + v * 8 + srow_in;        // 0..63
            int e = (r < 32) ? (e0 + r) : (256 + e0 + (r - 32));
            async_copy16(Wt + e * 256 + kc * 64 + sgg * 8,
                         Bs + r * 64 + sg * 8);
        }
        __builtin_amdgcn_sched_barrier(0);   // pin async copies before younger loads
        // --- A tile: transpose-pack ar (4 d-rows x 8 l) -> 8 x ds_write_b64 ---
#pragma unroll
        for (int j = 0; j < 8; ++j) {
            int q = j >> 1;
            uint sel = (j & 1) ? 0x07060302u : 0x05040100u;
            uint w0 = __builtin_amdgcn_perm(((const uint*)&ar[1])[q],
                                            ((const uint*)&ar[0])[q], sel);
            uint w1 = __builtin_amdgcn_perm(((const uint*)&ar[3])[q],
                                            ((const uint*)&ar[2])[q], sel);
            uint2 wv; wv.x = w0; wv.y = w1;
            int r = lb * 8 + j;              // r&7 = j, (r>>3)&7 = lb&7
            *(uint2*)(As + r * 64 + (((db >> 1) ^ j ^ (lb & 7)) * 8) + (db & 1) * 4) = wv;
        }
        // --- prefetch next-kc A slab (4 younger vmem ops, survive the barrier) ---
        if (kc < 3) {
#pragma unroll
            for (int rr = 0; rr < 4; ++rr)
                ar[rr] = *(const uint4*)(aPtr + (size_t)(kc + 1) * 64 * L_ + rr * L_);
            __builtin_amdgcn_sched_barrier(0);
            asm volatile("s_waitcnt vmcnt(4) lgkmcnt(0)" ::: "memory");
        } else {
            __builtin_amdgcn_sched_barrier(0);
            asm volatile("s_waitcnt vmcnt(0) lgkmcnt(0)" ::: "memory");
        }
        __builtin_amdgcn_s_barrier();
        __builtin_amdgcn_sched_barrier(0);
        // --- compute: bfr preloaded, af streamed ---
#pragma unroll
        for (int kk = 0; kk < 2; ++kk) {
            bf16x8 bfr[2];
            int g = kk * 4 + (lane >> 4);
            int gp = (g ^ (lane & 7)) * 8;
#pragma unroll
            for (int nt = 0; nt < 2; ++nt) {
                int n = nt * 32 + wn * 16 + (lane & 15);   // n&7 == lane&7
                bfr[nt] = *(const bf16x8*)(Bs + n * 64 + gp);
            }
#pragma unroll
            for (int mt = 0; mt < 4; ++mt) {
                int rowA = m0 + mt * 16 + (lane & 15);
                int gpA = (g ^ (lane & 7) ^ ((rowA >> 3) & 7)) * 8;
                bf16x8 af = *(const bf16x8*)(As + rowA * 64 + gpA);
#pragma unroll
                for (int nt = 0; nt < 2; ++nt)
                    acc[mt][nt] = __builtin_amdgcn_mfma_f32_16x16x32_bf16(
                        af, bfr[nt], acc[mt][nt], 0, 0, 0);
            }
        }
    }
    // --- prefetch residual x BEFORE the epilogue barriers ---
    float4 xf[4];
#pragma unroll
    for (int k = 0; k < 4; ++k) {
        int i = tid + k * 256;             // 0..1023
        int ll = i >> 3, e4 = i & 7;
        xf[k] = *(const float4*)(x + ((size_t)(b * L_ + l0 + ll)) * D_ + e0 + e4 * 4);
    }
    __syncthreads();
    float* epi = (float*)smem;             // [128 l][32 e] = 16 KB
    int row_in = (lane >> 4) * 4;
    int col = lane & 15;
#pragma unroll
    for (int mt = 0; mt < 4; ++mt) {
        f32x4 uacc = acc[mt][0];
        f32x4 vacc = acc[mt][1];
        int ee = wn * 16 + col;
        float bu = cb[e0 + ee], bv = cb[256 + e0 + ee];
#pragma unroll
        for (int r = 0; r < 4; ++r) {
            int ll = m0 + mt * 16 + row_in + r;
            float u = uacc[r] + bu;
            float v = vacc[r] + bv;
            float g = u * __builtin_amdgcn_rcpf(1.f + __expf(-v));
            epi[ll * 32 + (ee ^ ((ll & 4) ? 16 : 0))] = g;
        }
    }
    __syncthreads();
#pragma unroll
    for (int k = 0; k < 4; ++k) {
        int i = tid + k * 256;             // 0..1023
        int ll = i >> 3, e4 = i & 7;
        int exo = (e4 * 4) ^ ((ll & 4) ? 16 : 0);
        float4 gv = *(const float4*)(epi + ll * 32 + exo);
        size_t gidx = ((size_t)(b * L_ + l0 + ll)) * D_ + e0 + e4 * 4;
        float4 ov;
        ov.x = gv.x + xf[k].x; ov.y = gv.y + xf[k].y;
        ov.z = gv.z + xf[k].z; ov.w = gv.w + xf[k].w;
        *(float4*)(out + gidx) = ov;
    }
}

extern "C" void kernel_launch(void* const* d_in, const int* in_sizes, int n_in,
                              void* d_out, int out_size, void* d_ws, size_t ws_size,
                              hipStream_t stream) {
    const float* x  = (const float*)d_in[0];
    const float* rs = (const float*)d_in[1];
    const float* h0 = (const float*)d_in[2];
    const float* h1 = (const float*)d_in[3];
    const float* w  = (const float*)d_in[4];
    const float* cw = (const float*)d_in[5];
    const float* cb = (const float*)d_in[6];
    float* out = (float*)d_out;
    char* ws = (char*)d_ws;

    ushort* xtb = (ushort*)ws;                       // 16,777,216 B (bf16)
    ushort* ygt = (ushort*)(ws + 16777216);          // 16,777,216 B (bf16)
    ushort* Wt  = (ushort*)(ws + 33554432);          //    262,144 B (bf16)

    rms_wt_kernel<<<1056, 256, 0, stream>>>(x, rs, xtb, cw, Wt);
    cascade_kernel<<<1024, 256, 0, stream>>>(xtb, h0, h1, w, ygt);
    gemm_kernel<<<2048, 256, 0, stream>>>(ygt, Wt, cb, x, out);
}